// Round 2
// baseline (236.844 us; speedup 1.0000x reference)
//
#include <hip/hip_runtime.h>

#define LBL 32
#define NPIX (736 * 736)   // 541696 = 529 * 1024
#define BATCH 8
#define DELTA_AGG 0.5f
#define DELTA_DIS 1.5f
#define REG_W 0.001f

// ws layout per batch (floats):
//  [0,32)    cnt_k        (kernel-region counts; [0] is a presence flag only)
//  [32,160)  sum_k[32][4] (kernel-region emb sums, labels 1..31)
//  [160,192) sum_v        (aggregation loss sums per label)
//  [192,224) cnt_a        (aggregation pixel counts per label)
#define WSB 256

// -------- Pass 1: per-(batch,label) kernel-region count + emb sums --------
__global__ __launch_bounds__(256) void k1_seg(
    const float* __restrict__ emb, const int* __restrict__ inst,
    const float* __restrict__ kern, const float* __restrict__ mask,
    float* __restrict__ ws) {
  const int b = blockIdx.y;
  __shared__ float s_cnt[LBL];
  __shared__ float s_sum[LBL * 4];
  __shared__ int s_zero;
  if (threadIdx.x < LBL) s_cnt[threadIdx.x] = 0.f;
  if (threadIdx.x < LBL * 4) s_sum[threadIdx.x] = 0.f;
  if (threadIdx.x == 0) s_zero = 0;
  __syncthreads();

  const long base = (long)b * NPIX;
  const int q = blockIdx.x * 256 + threadIdx.x;  // float4 index within batch
  const int4 iv = ((const int4*)(inst + base))[q];
  const float4 kv = ((const float4*)(kern + base))[q];
  const float4 mv = ((const float4*)(mask + base))[q];
  const float* eb = emb + (long)b * 4 * NPIX;
  const float4 e0 = ((const float4*)(eb))[q];
  const float4 e1 = ((const float4*)(eb + NPIX))[q];
  const float4 e2 = ((const float4*)(eb + 2 * NPIX))[q];
  const float4 e3 = ((const float4*)(eb + 3 * NPIX))[q];

  const int labs[4] = {iv.x, iv.y, iv.z, iv.w};
  const float ks[4] = {kv.x, kv.y, kv.z, kv.w};
  const float ms[4] = {mv.x, mv.y, mv.z, mv.w};
  const float c0[4] = {e0.x, e0.y, e0.z, e0.w};
  const float c1[4] = {e1.x, e1.y, e1.z, e1.w};
  const float c2[4] = {e2.x, e2.y, e2.z, e2.w};
  const float c3[4] = {e3.x, e3.y, e3.z, e3.w};

  bool has0 = false;
#pragma unroll
  for (int j = 0; j < 4; j++) {
    const int lk = (ms[j] > 0.5f && ks[j] > 0.5f) ? labs[j] : 0;
    if (lk > 0) {
      atomicAdd(&s_cnt[lk], 1.0f);
      atomicAdd(&s_sum[lk * 4 + 0], c0[j]);
      atomicAdd(&s_sum[lk * 4 + 1], c1[j]);
      atomicAdd(&s_sum[lk * 4 + 2], c2[j]);
      atomicAdd(&s_sum[lk * 4 + 3], c3[j]);
    } else {
      has0 = true;
    }
  }
  if (has0) s_zero = 1;  // benign race: all writers store 1
  __syncthreads();

  float* wb = ws + b * WSB;
  if (threadIdx.x == 0 && s_zero) wb[0] = 1.0f;  // presence flag, benign race
  if (threadIdx.x > 0 && threadIdx.x < LBL) {
    const float v = s_cnt[threadIdx.x];
    if (v != 0.f) atomicAdd(&wb[threadIdx.x], v);
  }
  if (threadIdx.x < LBL * 4) {
    const float v = s_sum[threadIdx.x];
    if (v != 0.f) atomicAdd(&wb[32 + threadIdx.x], v);
  }
}

// -------- Pass 2: aggregation loss segment sums (means computed inline) -----
__global__ __launch_bounds__(256) void k3_agg(
    const float* __restrict__ emb, const int* __restrict__ inst,
    const float* __restrict__ mask, float* __restrict__ ws) {
  const int b = blockIdx.y;
  __shared__ float s_mean[LBL * 4];
  __shared__ float s_val[LBL];
  __shared__ float s_cnt[LBL];
  float* wb = ws + b * WSB;
  if (threadIdx.x < LBL * 4) {
    const int l = threadIdx.x >> 2;
    s_mean[threadIdx.x] =
        (l == 0) ? 0.f : wb[32 + threadIdx.x] / fmaxf(wb[l], 1.0f);
  }
  if (threadIdx.x < LBL) {
    s_val[threadIdx.x] = 0.f;
    s_cnt[threadIdx.x] = 0.f;
  }
  __syncthreads();

  const long base = (long)b * NPIX;
  const int q = blockIdx.x * 256 + threadIdx.x;
  const int4 iv = ((const int4*)(inst + base))[q];
  const float4 mv = ((const float4*)(mask + base))[q];
  const float* eb = emb + (long)b * 4 * NPIX;
  const float4 e0 = ((const float4*)(eb))[q];
  const float4 e1 = ((const float4*)(eb + NPIX))[q];
  const float4 e2 = ((const float4*)(eb + 2 * NPIX))[q];
  const float4 e3 = ((const float4*)(eb + 3 * NPIX))[q];

  const int labs[4] = {iv.x, iv.y, iv.z, iv.w};
  const float ms[4] = {mv.x, mv.y, mv.z, mv.w};
  const float c0[4] = {e0.x, e0.y, e0.z, e0.w};
  const float c1[4] = {e1.x, e1.y, e1.z, e1.w};
  const float c2[4] = {e2.x, e2.y, e2.z, e2.w};
  const float c3[4] = {e3.x, e3.y, e3.z, e3.w};

#pragma unroll
  for (int j = 0; j < 4; j++) {
    const int li = (ms[j] > 0.5f) ? labs[j] : 0;
    if (li > 0) {  // label 0 excluded from l_agg (nz mask)
      const float d0 = c0[j] - s_mean[li * 4 + 0];
      const float d1 = c1[j] - s_mean[li * 4 + 1];
      const float d2 = c2[j] - s_mean[li * 4 + 2];
      const float d3 = c3[j] - s_mean[li * 4 + 3];
      const float sq = d0 * d0 + d1 * d1 + d2 * d2 + d3 * d3;
      const float dist = (sq > 0.f) ? sqrtf(sq) : 0.f;
      const float t = fmaxf(dist - DELTA_AGG, 0.f);
      const float val = logf(fmaf(t, t, 1.0f));
      atomicAdd(&s_val[li], val);
      atomicAdd(&s_cnt[li], 1.0f);
    }
  }
  __syncthreads();
  if (threadIdx.x < LBL) {
    const float v = s_val[threadIdx.x], c = s_cnt[threadIdx.x];
    if (v != 0.f) atomicAdd(&wb[160 + threadIdx.x], v);
    if (c != 0.f) atomicAdd(&wb[192 + threadIdx.x], c);
  }
}

// -------- Finalize: one wave per batch --------
__global__ __launch_bounds__(64) void k4_final(const float* __restrict__ ws,
                                               float* __restrict__ out) {
  const int b = blockIdx.x;
  const int lane = threadIdx.x;
  const float* wb = ws + b * WSB;
  __shared__ float sm[LBL * 4];
  __shared__ float sc[LBL];
  if (lane < LBL) {
    const float c = wb[lane];
    sc[lane] = c;
    const float inv = 1.0f / fmaxf(c, 1.0f);
#pragma unroll
    for (int d = 0; d < 4; d++)
      sm[lane * 4 + d] = (lane == 0) ? 0.f : wb[32 + lane * 4 + d] * inv;
  }
  __syncthreads();

  const bool pres = (lane < LBL) && (sc[lane] > 0.f);
  const unsigned long long bal_p = __ballot(pres);
  const int num_instance = __popcll(bal_p);
  const bool nz = pres && (lane > 0);
  const unsigned long long bal_nz = __ballot(nz);

  // l_agg contribution
  float agg = 0.f;
  if (nz) agg = wb[160 + lane] / fmaxf(wb[192 + lane], 1.0f);

  // l_reg contribution
  float reg = 0.f;
  if (pres) {
    float sq = 0.f;
#pragma unroll
    for (int d = 0; d < 4; d++) sq += sm[lane * 4 + d] * sm[lane * 4 + d];
    const float nrm = (sq > 0.f) ? sqrtf(sq) : 0.f;
    reg = logf(nrm + 1.0f);
  }

  // l_dis: all ordered pairs i != j, both nz (1024 pairs / 64 lanes)
  float dis = 0.f, npair = 0.f;
  for (int pi = lane; pi < LBL * LBL; pi += 64) {
    const int i = pi >> 5, j = pi & 31;
    if (i != j && ((bal_nz >> i) & 1ull) && ((bal_nz >> j) & 1ull)) {
      float sq = 0.f;
#pragma unroll
      for (int d = 0; d < 4; d++) {
        const float df = sm[i * 4 + d] - sm[j * 4 + d];
        sq += df * df;
      }
      const float pdist = (sq > 0.f) ? sqrtf(sq) : 0.f;
      const float t = fmaxf(2.0f * DELTA_DIS - pdist, 0.f);
      dis += logf(fmaf(t, t, 1.0f));
      npair += 1.0f;
    }
  }

#pragma unroll
  for (int o = 32; o > 0; o >>= 1) {
    agg += __shfl_down(agg, o);
    reg += __shfl_down(reg, o);
    dis += __shfl_down(dis, o);
    npair += __shfl_down(npair, o);
  }

  if (lane == 0) {
    const float l_agg = agg / fmaxf((float)(num_instance - 1), 1.0f);
    const float l_dis = (num_instance > 2) ? dis / fmaxf(npair, 1.0f) : 0.f;
    const float l_reg = reg / fmaxf((float)num_instance, 1.0f) * REG_W;
    const float loss = l_agg + l_dis + l_reg;
    out[b] = (num_instance <= 1) ? 0.f : loss;
  }
}

extern "C" void kernel_launch(void* const* d_in, const int* in_sizes, int n_in,
                              void* d_out, int out_size, void* d_ws,
                              size_t ws_size, hipStream_t stream) {
  const float* emb = (const float*)d_in[0];
  const int* instance = (const int*)d_in[1];
  const float* kern = (const float*)d_in[2];
  const float* mask = (const float*)d_in[3];
  float* out = (float*)d_out;
  float* ws = (float*)d_ws;

  // ws is re-poisoned to 0xAA before every launch — zero what we accumulate.
  hipMemsetAsync(d_ws, 0, BATCH * WSB * sizeof(float), stream);

  dim3 grid(NPIX / 1024, BATCH);  // 529 x 8 blocks, 4 px per thread
  k1_seg<<<grid, 256, 0, stream>>>(emb, instance, kern, mask, ws);
  k3_agg<<<grid, 256, 0, stream>>>(emb, instance, mask, ws);
  k4_final<<<BATCH, 64, 0, stream>>>(ws, out);
}

// Round 3
// 190.476 us; speedup vs baseline: 1.2434x; 1.2434x over previous
//
#include <hip/hip_runtime.h>

#define LBL 32
#define NPIX (736 * 736)     // 541696
#define NQ (NPIX / 4)        // 135424 float4-quads per batch
#define BATCH 8
#define G 64                 // streaming blocks per batch
#define TPB 256
#define STRIDE (G * TPB)     // 16384 threads per batch
#define DELTA_AGG 0.5f
#define DELTA_DIS 1.5f
#define REG_W 0.001f

// ws layout (floats), ~465 KB total:
//  partA: [0, 8*64*160)   per (batch,block): cnt[32] ([0]=saw-label-0 flag), sum[32*4]
//  red:   [81920, +8*192) per batch: cnt_k[32], mean[32*4], pad
//  partC: [83456, +8*64*64) per (batch,block): val[32], cnt[32]
#define PA_BASE 0
#define RED_BASE 81920
#define PC_BASE 83456

// -------- Pass A: per-(batch,label) kernel-region count + emb sums ----------
__global__ __launch_bounds__(256) void kA(
    const float* __restrict__ emb, const int* __restrict__ inst,
    const float* __restrict__ kern, const float* __restrict__ mask,
    float* __restrict__ ws) {
  const int b = blockIdx.y;
  __shared__ float s_cnt[LBL];      // [0] is the "saw label 0" flag
  __shared__ float s_sum[LBL * 4];
  if (threadIdx.x < LBL) s_cnt[threadIdx.x] = 0.f;
  if (threadIdx.x < LBL * 4) s_sum[threadIdx.x] = 0.f;
  __syncthreads();

  const long base = (long)b * NPIX;
  const float* eb = emb + (long)b * 4 * NPIX;
  const int4* ip = (const int4*)(inst + base);
  const float4* kp = (const float4*)(kern + base);
  const float4* mp = (const float4*)(mask + base);
  const float4* p0 = (const float4*)(eb);
  const float4* p1 = (const float4*)(eb + NPIX);
  const float4* p2 = (const float4*)(eb + 2 * NPIX);
  const float4* p3 = (const float4*)(eb + 3 * NPIX);

  bool has0 = false;
  for (int q = blockIdx.x * TPB + threadIdx.x; q < NQ; q += STRIDE) {
    const int4 iv = ip[q];
    const float4 kv = kp[q];
    const float4 mv = mp[q];
    const float4 e0 = p0[q], e1 = p1[q], e2 = p2[q], e3 = p3[q];
    const int labs[4] = {iv.x, iv.y, iv.z, iv.w};
    const float ks[4] = {kv.x, kv.y, kv.z, kv.w};
    const float ms[4] = {mv.x, mv.y, mv.z, mv.w};
    const float c0[4] = {e0.x, e0.y, e0.z, e0.w};
    const float c1[4] = {e1.x, e1.y, e1.z, e1.w};
    const float c2[4] = {e2.x, e2.y, e2.z, e2.w};
    const float c3[4] = {e3.x, e3.y, e3.z, e3.w};
#pragma unroll
    for (int j = 0; j < 4; j++) {
      const int lk = (ms[j] > 0.5f && ks[j] > 0.5f) ? labs[j] : 0;
      if (lk > 0) {
        atomicAdd(&s_cnt[lk], 1.0f);
        atomicAdd(&s_sum[lk * 4 + 0], c0[j]);
        atomicAdd(&s_sum[lk * 4 + 1], c1[j]);
        atomicAdd(&s_sum[lk * 4 + 2], c2[j]);
        atomicAdd(&s_sum[lk * 4 + 3], c3[j]);
      } else {
        has0 = true;
      }
    }
  }
  if (has0) s_cnt[0] = 1.0f;  // benign race: all writers store 1
  __syncthreads();

  // Plain coalesced partial store — NO global atomics.
  float* po = ws + PA_BASE + (size_t)(b * G + blockIdx.x) * 160;
  const int t = threadIdx.x;
  if (t < 160) po[t] = (t < 32) ? s_cnt[t] : s_sum[t - 32];
}

// -------- Reduce A partials -> cnt_k + means --------------------------------
__global__ __launch_bounds__(256) void kB(float* __restrict__ ws) {
  const int b = blockIdx.x, t = threadIdx.x;
  __shared__ float sred[160];
  if (t < 160) {
    const float* pa = ws + PA_BASE + (size_t)(b * G) * 160 + t;
    float s = 0.f;
#pragma unroll 8
    for (int g = 0; g < G; g++) s += pa[(size_t)g * 160];
    sred[t] = s;
  }
  __syncthreads();
  float* rd = ws + RED_BASE + b * 192;
  if (t < 160) {
    if (t < 32) {
      rd[t] = sred[t];  // cnt_k (index 0: presence flag sum)
    } else {
      const int l = (t - 32) >> 2;
      rd[t] = (l == 0) ? 0.f : sred[t] / fmaxf(sred[l], 1.0f);  // mean
    }
  }
}

// -------- Pass C: aggregation loss segment sums -----------------------------
__global__ __launch_bounds__(256) void kC(
    const float* __restrict__ emb, const int* __restrict__ inst,
    const float* __restrict__ mask, float* __restrict__ ws) {
  const int b = blockIdx.y;
  __shared__ float s_mean[LBL * 4];
  __shared__ float s_val[LBL];
  __shared__ float s_cnt[LBL];
  const float* rd = ws + RED_BASE + b * 192;
  if (threadIdx.x < LBL * 4) s_mean[threadIdx.x] = rd[32 + threadIdx.x];
  if (threadIdx.x < LBL) {
    s_val[threadIdx.x] = 0.f;
    s_cnt[threadIdx.x] = 0.f;
  }
  __syncthreads();

  const long base = (long)b * NPIX;
  const float* eb = emb + (long)b * 4 * NPIX;
  const int4* ip = (const int4*)(inst + base);
  const float4* mp = (const float4*)(mask + base);
  const float4* p0 = (const float4*)(eb);
  const float4* p1 = (const float4*)(eb + NPIX);
  const float4* p2 = (const float4*)(eb + 2 * NPIX);
  const float4* p3 = (const float4*)(eb + 3 * NPIX);

  for (int q = blockIdx.x * TPB + threadIdx.x; q < NQ; q += STRIDE) {
    const int4 iv = ip[q];
    const float4 mv = mp[q];
    const float4 e0 = p0[q], e1 = p1[q], e2 = p2[q], e3 = p3[q];
    const int labs[4] = {iv.x, iv.y, iv.z, iv.w};
    const float ms[4] = {mv.x, mv.y, mv.z, mv.w};
    const float c0[4] = {e0.x, e0.y, e0.z, e0.w};
    const float c1[4] = {e1.x, e1.y, e1.z, e1.w};
    const float c2[4] = {e2.x, e2.y, e2.z, e2.w};
    const float c3[4] = {e3.x, e3.y, e3.z, e3.w};
#pragma unroll
    for (int j = 0; j < 4; j++) {
      const int li = (ms[j] > 0.5f) ? labs[j] : 0;
      if (li > 0) {  // label 0 excluded from l_agg (nz mask)
        const float d0 = c0[j] - s_mean[li * 4 + 0];
        const float d1 = c1[j] - s_mean[li * 4 + 1];
        const float d2 = c2[j] - s_mean[li * 4 + 2];
        const float d3 = c3[j] - s_mean[li * 4 + 3];
        const float sq = d0 * d0 + d1 * d1 + d2 * d2 + d3 * d3;
        const float dist = (sq > 0.f) ? sqrtf(sq) : 0.f;
        const float tt = fmaxf(dist - DELTA_AGG, 0.f);
        atomicAdd(&s_val[li], logf(fmaf(tt, tt, 1.0f)));
        atomicAdd(&s_cnt[li], 1.0f);
      }
    }
  }
  __syncthreads();
  float* po = ws + PC_BASE + (size_t)(b * G + blockIdx.x) * 64;
  const int t = threadIdx.x;
  if (t < 64) po[t] = (t < 32) ? s_val[t] : s_cnt[t - 32];
}

// -------- Reduce C + finalize: one wave per batch ---------------------------
__global__ __launch_bounds__(64) void kD(const float* __restrict__ ws,
                                         float* __restrict__ out) {
  const int b = blockIdx.x;
  const int lane = threadIdx.x;

  // reduce partC: lane v<32 -> sum_v[v]; lane v>=32 -> cnt_a[v-32]
  const float* pc = ws + PC_BASE + (size_t)(b * G) * 64 + lane;
  float s = 0.f;
#pragma unroll 8
  for (int g = 0; g < G; g++) s += pc[(size_t)g * 64];
  const float cnt_partner = __shfl(s, lane + 32);  // cnt_a for lanes < 32

  const float* rd = ws + RED_BASE + b * 192;
  __shared__ float sm[LBL * 4];
  __shared__ float sc[LBL];
  if (lane < LBL) sc[lane] = rd[lane];
  sm[lane] = rd[32 + lane];
  sm[64 + lane] = rd[96 + lane];
  __syncthreads();

  const bool pres = (lane < LBL) && (sc[lane] > 0.f);
  const unsigned long long bal_p = __ballot(pres);
  const int num_instance = __popcll(bal_p);
  const bool nz = pres && (lane > 0);
  const unsigned long long bal_nz = __ballot(nz);

  float agg = 0.f;
  if (nz) agg = s / fmaxf(cnt_partner, 1.0f);

  float reg = 0.f;
  if (pres) {
    float sq = 0.f;
#pragma unroll
    for (int d = 0; d < 4; d++) sq += sm[lane * 4 + d] * sm[lane * 4 + d];
    const float nrm = (sq > 0.f) ? sqrtf(sq) : 0.f;
    reg = logf(nrm + 1.0f);
  }

  float dis = 0.f, npair = 0.f;
  for (int pi = lane; pi < LBL * LBL; pi += 64) {
    const int i = pi >> 5, j = pi & 31;
    if (i != j && ((bal_nz >> i) & 1ull) && ((bal_nz >> j) & 1ull)) {
      float sq = 0.f;
#pragma unroll
      for (int d = 0; d < 4; d++) {
        const float df = sm[i * 4 + d] - sm[j * 4 + d];
        sq += df * df;
      }
      const float pdist = (sq > 0.f) ? sqrtf(sq) : 0.f;
      const float tt = fmaxf(2.0f * DELTA_DIS - pdist, 0.f);
      dis += logf(fmaf(tt, tt, 1.0f));
      npair += 1.0f;
    }
  }

#pragma unroll
  for (int o = 32; o > 0; o >>= 1) {
    agg += __shfl_down(agg, o);
    reg += __shfl_down(reg, o);
    dis += __shfl_down(dis, o);
    npair += __shfl_down(npair, o);
  }

  if (lane == 0) {
    const float l_agg = agg / fmaxf((float)(num_instance - 1), 1.0f);
    const float l_dis = (num_instance > 2) ? dis / fmaxf(npair, 1.0f) : 0.f;
    const float l_reg = reg / fmaxf((float)num_instance, 1.0f) * REG_W;
    const float loss = l_agg + l_dis + l_reg;
    out[b] = (num_instance <= 1) ? 0.f : loss;
  }
}

extern "C" void kernel_launch(void* const* d_in, const int* in_sizes, int n_in,
                              void* d_out, int out_size, void* d_ws,
                              size_t ws_size, hipStream_t stream) {
  const float* emb = (const float*)d_in[0];
  const int* instance = (const int*)d_in[1];
  const float* kern = (const float*)d_in[2];
  const float* mask = (const float*)d_in[3];
  float* out = (float*)d_out;
  float* ws = (float*)d_ws;

  // No memset: every ws word we read is plain-stored by a prior kernel.
  dim3 grid(G, BATCH);  // 512 streaming blocks, grid-stride over pixels
  kA<<<grid, TPB, 0, stream>>>(emb, instance, kern, mask, ws);
  kB<<<BATCH, TPB, 0, stream>>>(ws);
  kC<<<grid, TPB, 0, stream>>>(emb, instance, mask, ws);
  kD<<<BATCH, 64, 0, stream>>>(ws, out);
}